// Round 9
// baseline (209.650 us; speedup 1.0000x reference)
//
#include <hip/hip_runtime.h>
#include <hip/hip_bf16.h>
#include <hip/hip_fp16.h>

#define NDIM_IN 128
#define HID 64

#define BINW 128          // dst values per bin
#define NB   782          // ceil(100000/128)
#define NC   256          // phase-1 block count (chunk mapping shared hist/scatter)
#define CAP  3072         // LDS edge buffer per bin (mean 2046, +22 sigma)
#define CAPE 1024         // staged col indices per spmm block (mean 512, +22 sigma)

typedef _Float16 f16x8 __attribute__((ext_vector_type(8)));
typedef float f32x4 __attribute__((ext_vector_type(4)));

// f16-source fused accumulate: acc += f32(f16_half(src)) * 1.0 — bit-identical
// to cvt+add (f16->f32 exact, *1.0 exact), 1 VALU inst instead of 2.
// NOTE: macro params must NOT be named x/y/z/w — the preprocessor substitutes
// member-name tokens too (R7 compile failure).
#define MIX_LO(acc, hsrc) \
  asm("v_fma_mix_f32 %0, %1, %2, %0 op_sel:[0,0,0] op_sel_hi:[1,0,0]" \
      : "+v"(acc) : "v"(hsrc), "v"(one))
#define MIX_HI(acc, hsrc) \
  asm("v_fma_mix_f32 %0, %1, %2, %0 op_sel:[1,0,0] op_sel_hi:[1,0,0]" \
      : "+v"(acc) : "v"(hsrc), "v"(one))
#define ACC8(a, q) do { \
  MIX_LO(a[0], (q).x); MIX_HI(a[1], (q).x); \
  MIX_LO(a[2], (q).y); MIX_HI(a[3], (q).y); \
  MIX_LO(a[4], (q).z); MIX_HI(a[5], (q).z); \
  MIX_LO(a[6], (q).w); MIX_HI(a[7], (q).w); } while (0)

// ---------------------------------------------------------------------------
// Phase 1a: per-block LDS histogram over bins + DYNAMIC within-bin range
// reservation: atomicAdd(&gofs[bin], h[bin]) returns this block's exclusive
// offset inside the bin -> stored in histT (what scan1's S used to provide).
// gofs must be zeroed before launch (3KB memsetAsync); its final value is
// the per-bin total, consumed by scatter's LDS scan. scan1 kernel DELETED.
// ---------------------------------------------------------------------------
__global__ __launch_bounds__(1024) void hist_k(const int* __restrict__ dst,
                                               int* __restrict__ histT,
                                               int* __restrict__ gofs, int E) {
  __shared__ int h[NB];
  for (int i = threadIdx.x; i < NB; i += 1024) h[i] = 0;
  __syncthreads();
  int E4 = E >> 2;
  int chunk = (E4 + NC - 1) / NC;
  int beg = blockIdx.x * chunk;
  int end = min(E4, beg + chunk);
  const int4* __restrict__ d4 = (const int4*)dst;
  for (int i = beg + (int)threadIdx.x; i < end; i += 1024) {
    int4 d = d4[i];
    atomicAdd(&h[d.x >> 7], 1);
    atomicAdd(&h[d.y >> 7], 1);
    atomicAdd(&h[d.z >> 7], 1);
    atomicAdd(&h[d.w >> 7], 1);
  }
  __syncthreads();
  for (int i = threadIdx.x; i < NB; i += 1024) {
    int c = h[i];
    int ofs = atomicAdd(&gofs[i], c);     // reserve range within bin
    histT[i * NC + blockIdx.x] = ofs;     // this block's within-bin offset
  }
}

// ---------------------------------------------------------------------------
// Phase 1c: scatter packed (src<<7 | dst&127) into tmp, grouped by bin.
// LDS scan of gofs (782 totals) -> bin bases; block 0 publishes to bsum_out
// for binsort_k. S holds the dynamic within-bin offsets from hist_k.
// ---------------------------------------------------------------------------
__global__ __launch_bounds__(1024) void scatter_k(const int* __restrict__ src,
                                                  const int* __restrict__ dst,
                                                  const int* __restrict__ S,
                                                  const int* __restrict__ gofs,
                                                  int* __restrict__ bsum_out,
                                                  int* __restrict__ tmp, int E) {
  __shared__ int cur[NB];
  __shared__ int sc[1024];
  int t = threadIdx.x;
  int v = (t < NB) ? gofs[t] : 0;
  sc[t] = v;
  __syncthreads();
  for (int off = 1; off < 1024; off <<= 1) {
    int x = (t >= off) ? sc[t - off] : 0;
    __syncthreads();
    sc[t] += x;
    __syncthreads();
  }
  if (t < NB) {
    int ex = sc[t] - v;                       // exclusive bin base
    cur[t] = S[t * NC + blockIdx.x] + ex;
    if (blockIdx.x == 0) bsum_out[t] = ex;    // publish for binsort_k
  }
  __syncthreads();
  int E4 = E >> 2;
  int chunk = (E4 + NC - 1) / NC;
  int beg = blockIdx.x * chunk;
  int end = min(E4, beg + chunk);
  const int4* __restrict__ d4 = (const int4*)dst;
  const int4* __restrict__ s4 = (const int4*)src;
  for (int i = beg + (int)threadIdx.x; i < end; i += 1024) {
    int4 d = d4[i];
    int4 sv = s4[i];
    int p0 = atomicAdd(&cur[d.x >> 7], 1); tmp[p0] = (sv.x << 7) | (d.x & 127);
    int p1 = atomicAdd(&cur[d.y >> 7], 1); tmp[p1] = (sv.y << 7) | (d.y & 127);
    int p2 = atomicAdd(&cur[d.z >> 7], 1); tmp[p2] = (sv.z << 7) | (d.z & 127);
    int p3 = atomicAdd(&cur[d.w >> 7], 1); tmp[p3] = (sv.w << 7) | (d.w & 127);
  }
}

// ---------------------------------------------------------------------------
// Phase 2: one block per bin; in-LDS counting sort -> col, rp, dinv.
// ---------------------------------------------------------------------------
__global__ __launch_bounds__(256) void binsort_k(const int* __restrict__ tmp,
                                                 const int* __restrict__ bsum,
                                                 int* __restrict__ col,
                                                 int* __restrict__ rp,
                                                 float* __restrict__ dinv,
                                                 int n, int E) {
  int bin = blockIdx.x;
  int base = bsum[bin];
  int end = (bin == NB - 1) ? E : bsum[bin + 1];
  int m = end - base;
  __shared__ int cnt[BINW];
  __shared__ int offs[BINW];
  __shared__ int cur[BINW];
  __shared__ int buf[CAP];
  int t = threadIdx.x;
  if (t < BINW) cnt[t] = 0;
  __syncthreads();
  for (int i = t; i < m; i += 256) {
    int p = tmp[base + i];
    atomicAdd(&cnt[p & (BINW - 1)], 1);
  }
  __syncthreads();
  if (t < BINW) offs[t] = cnt[t];
  __syncthreads();
  for (int off = 1; off < BINW; off <<= 1) {
    int x = (t < BINW && t >= off) ? offs[t - off] : 0;
    __syncthreads();
    if (t < BINW) offs[t] += x;
    __syncthreads();
  }
  if (t < BINW) {
    int ex = offs[t] - cnt[t];
    cur[t] = ex;
    int v = bin * BINW + t;
    if (v < n) {
      rp[v] = base + ex;
      dinv[v] = rsqrtf((float)cnt[t] + 1.0f);  // +1 = self loop
    }
  }
  if (bin == NB - 1 && t == 0) rp[n] = E;
  __syncthreads();
  for (int i = t; i < m; i += 256) {
    int p = tmp[base + i];
    int r = atomicAdd(&cur[p & (BINW - 1)], 1);
    if (r < CAP) buf[r] = p >> 7;
  }
  __syncthreads();
  int mm = min(m, CAP);
  for (int i = t; i < mm; i += 256) col[base + i] = buf[i];
}

// ---------------------------------------------------------------------------
// MFMA dense transform: T' = (X @ W) * dinv[row], output fp16.
// FP16IN=1: input rows already fp16 (inter-layer H) -> direct f16x8 loads.
// Layouts (verified m89/m91/m120): A[m=lane&15][k=quad*8+j],
// B[k=quad*8+j][n=lane&15], D[row=quad*4+r][col=lane&15].
// ---------------------------------------------------------------------------
template <int K, int FP16IN>
__global__ __launch_bounds__(256) void gemm_mfma(const void* __restrict__ Xv,
                                                 const float* __restrict__ W,
                                                 const float* __restrict__ dinv,
                                                 __half* __restrict__ T,
                                                 int n, int ntiles) {
  constexpr int NCH = K / 32;
  __shared__ float Ds[4][16 * 68];
  int wv = threadIdx.x >> 6;
  int lane = threadIdx.x & 63;
  int colx = lane & 15;
  int quad = lane >> 4;

  // B fragments: whole W, fp16, stationary
  f16x8 bf[4][NCH];
#pragma unroll
  for (int t = 0; t < 4; t++)
#pragma unroll
    for (int c = 0; c < NCH; c++) {
      f16x8 b;
#pragma unroll
      for (int j = 0; j < 8; j++)
        b[j] = (_Float16)W[(32 * c + quad * 8 + j) * 64 + 16 * t + colx];
      bf[t][c] = b;
    }

  for (int tile = blockIdx.x * 4 + wv; tile < ntiles; tile += gridDim.x * 4) {
    int node0 = tile * 16;
    f32x4 acc[4] = {{0.f, 0.f, 0.f, 0.f}, {0.f, 0.f, 0.f, 0.f},
                    {0.f, 0.f, 0.f, 0.f}, {0.f, 0.f, 0.f, 0.f}};
    int arow = min(node0 + colx, n - 1);
#pragma unroll
    for (int c = 0; c < NCH; c++) {
      f16x8 a;
      if constexpr (FP16IN) {
        const _Float16* __restrict__ xr = (const _Float16*)Xv + (size_t)arow * K;
        a = *(const f16x8*)(xr + 32 * c + quad * 8);
      } else {
        const float* __restrict__ xr = (const float*)Xv + (size_t)arow * K;
        float4 x0 = *(const float4*)(xr + 32 * c + quad * 8);
        float4 x1 = *(const float4*)(xr + 32 * c + quad * 8 + 4);
        a[0] = (_Float16)x0.x; a[1] = (_Float16)x0.y;
        a[2] = (_Float16)x0.z; a[3] = (_Float16)x0.w;
        a[4] = (_Float16)x1.x; a[5] = (_Float16)x1.y;
        a[6] = (_Float16)x1.z; a[7] = (_Float16)x1.w;
      }
#pragma unroll
      for (int t = 0; t < 4; t++)
        acc[t] = __builtin_amdgcn_mfma_f32_16x16x32_f16(a, bf[t][c], acc[t], 0, 0, 0);
    }
    // epilogue: scale rows by dinv, transpose through LDS, emit fp16
    float dv[4];
#pragma unroll
    for (int r = 0; r < 4; r++) {
      int nd = min(node0 + quad * 4 + r, n - 1);
      dv[r] = dinv[nd];
    }
#pragma unroll
    for (int t = 0; t < 4; t++)
#pragma unroll
      for (int r = 0; r < 4; r++)
        Ds[wv][(quad * 4 + r) * 68 + 16 * t + colx] = acc[t][r] * dv[r];
    int nd = node0 + colx;
    const float* __restrict__ row = &Ds[wv][colx * 68 + quad * 16];
    float4 y0 = *(const float4*)(row + 0);
    float4 y1 = *(const float4*)(row + 4);
    float4 y2 = *(const float4*)(row + 8);
    float4 y3 = *(const float4*)(row + 12);
    f16x8 o0, o1;
    o0[0] = (_Float16)y0.x; o0[1] = (_Float16)y0.y;
    o0[2] = (_Float16)y0.z; o0[3] = (_Float16)y0.w;
    o0[4] = (_Float16)y1.x; o0[5] = (_Float16)y1.y;
    o0[6] = (_Float16)y1.z; o0[7] = (_Float16)y1.w;
    o1[0] = (_Float16)y2.x; o1[1] = (_Float16)y2.y;
    o1[2] = (_Float16)y2.z; o1[3] = (_Float16)y2.w;
    o1[4] = (_Float16)y3.x; o1[5] = (_Float16)y3.y;
    o1[6] = (_Float16)y3.z; o1[7] = (_Float16)y3.w;
    if (nd < n) {
      uint4* __restrict__ o = (uint4*)(T + (size_t)nd * 64 + quad * 16);
      o[0] = *(uint4*)&o0;
      o[1] = *(uint4*)&o1;
    }
  }
}

// ---------------------------------------------------------------------------
// SpMM gather: GROUP-per-node, LDS-staged col indices (R5), 8-edge unroll
// (this round: 8 independent col->T chains to hide Infinity-Cache latency;
// R4 showed depth 2->4 still paid), 2 accumulator sets, v_fma_mix.
// Always emits fp16 H (layer3's head input now fp16 too).
// NOTE R3 lesson: do NOT fuse the MLP head here (VGPR/LDS kill occupancy).
// ---------------------------------------------------------------------------
__global__ __launch_bounds__(256) void spmm_relu(const int* __restrict__ rp,
                                                 const int* __restrict__ col,
                                                 const __half* __restrict__ T,
                                                 const float* __restrict__ dinv,
                                                 const float* __restrict__ bias,
                                                 __half* __restrict__ Hout, int n) {
  __shared__ int colS[CAPE];
  int v0 = blockIdx.x * 32;
  int ebeg = rp[v0];
  int eend = rp[min(v0 + 32, n)];
  int m = eend - ebeg;
  int mstage = min(m, CAPE);
  for (int i = threadIdx.x; i < mstage; i += 256) colS[i] = col[ebeg + i];
  __syncthreads();

  int lane = threadIdx.x & 63;
  int wv = threadIdx.x >> 6;
  int g = lane >> 3;
  int sub = lane & 7;
  int v = v0 + wv * 8 + g;
  bool valid = v < n;
  if (!valid) v = n - 1;
  const uint4* __restrict__ T8 = (const uint4*)T;
  int beg = rp[v];
  int end = rp[v + 1];
  int lim = min(end, ebeg + CAPE);   // staged portion of this node's edges

  float one = 1.0f;
  float a0[8], a1[8];
#pragma unroll
  for (int j = 0; j < 8; j++) { a0[j] = 0.f; a1[j] = 0.f; }
  // self-loop row (every group loads its own node's row slice)
  {
    uint4 q0 = T8[(size_t)v * 8 + sub];
    ACC8(a0, q0);
  }
  int e = beg;
  for (; e + 8 <= lim; e += 8) {
    int s0 = colS[e - ebeg];
    int s1 = colS[e - ebeg + 1];
    int s2 = colS[e - ebeg + 2];
    int s3 = colS[e - ebeg + 3];
    int s4 = colS[e - ebeg + 4];
    int s5 = colS[e - ebeg + 5];
    int s6 = colS[e - ebeg + 6];
    int s7 = colS[e - ebeg + 7];
    uint4 q0 = T8[(size_t)s0 * 8 + sub];
    uint4 q1 = T8[(size_t)s1 * 8 + sub];
    uint4 q2 = T8[(size_t)s2 * 8 + sub];
    uint4 q3 = T8[(size_t)s3 * 8 + sub];
    uint4 q4 = T8[(size_t)s4 * 8 + sub];
    uint4 q5 = T8[(size_t)s5 * 8 + sub];
    uint4 q6 = T8[(size_t)s6 * 8 + sub];
    uint4 q7 = T8[(size_t)s7 * 8 + sub];
    ACC8(a0, q0);
    ACC8(a1, q1);
    ACC8(a0, q2);
    ACC8(a1, q3);
    ACC8(a0, q4);
    ACC8(a1, q5);
    ACC8(a0, q6);
    ACC8(a1, q7);
  }
  for (; e + 4 <= lim; e += 4) {
    int s0 = colS[e - ebeg];
    int s1 = colS[e - ebeg + 1];
    int s2 = colS[e - ebeg + 2];
    int s3 = colS[e - ebeg + 3];
    uint4 q0 = T8[(size_t)s0 * 8 + sub];
    uint4 q1 = T8[(size_t)s1 * 8 + sub];
    uint4 q2 = T8[(size_t)s2 * 8 + sub];
    uint4 q3 = T8[(size_t)s3 * 8 + sub];
    ACC8(a0, q0);
    ACC8(a1, q1);
    ACC8(a0, q2);
    ACC8(a1, q3);
  }
  for (; e < lim; ++e) {
    int s0 = colS[e - ebeg];
    uint4 q0 = T8[(size_t)s0 * 8 + sub];
    ACC8(a0, q0);
  }
  // overflow fallback (cold; only if block range exceeded CAPE)
  for (; e < end; ++e) {
    int s0 = col[e];
    uint4 q0 = T8[(size_t)s0 * 8 + sub];
    ACC8(a0, q0);
  }
  float di = dinv[v];
  const float4* __restrict__ b4 = (const float4*)bias;
  float4 bA = b4[sub * 2], bB = b4[sub * 2 + 1];
  float4 rA, rB;
  rA.x = di * (a0[0] + a1[0]) + bA.x;
  rA.y = di * (a0[1] + a1[1]) + bA.y;
  rA.z = di * (a0[2] + a1[2]) + bA.z;
  rA.w = di * (a0[3] + a1[3]) + bA.w;
  rB.x = di * (a0[4] + a1[4]) + bB.x;
  rB.y = di * (a0[5] + a1[5]) + bB.y;
  rB.z = di * (a0[6] + a1[6]) + bB.z;
  rB.w = di * (a0[7] + a1[7]) + bB.w;
  rA.x = rA.x > 0.f ? rA.x : 0.f;  rA.y = rA.y > 0.f ? rA.y : 0.f;
  rA.z = rA.z > 0.f ? rA.z : 0.f;  rA.w = rA.w > 0.f ? rA.w : 0.f;
  rB.x = rB.x > 0.f ? rB.x : 0.f;  rB.y = rB.y > 0.f ? rB.y : 0.f;
  rB.z = rB.z > 0.f ? rB.z : 0.f;  rB.w = rB.w > 0.f ? rB.w : 0.f;
  if (valid) {
    f16x8 o;
    o[0] = (_Float16)rA.x; o[1] = (_Float16)rA.y;
    o[2] = (_Float16)rA.z; o[3] = (_Float16)rA.w;
    o[4] = (_Float16)rB.x; o[5] = (_Float16)rB.y;
    o[6] = (_Float16)rB.z; o[7] = (_Float16)rB.w;
    uint4* __restrict__ o4 = (uint4*)(Hout + (size_t)v * HID + sub * 8);
    *o4 = *(uint4*)&o;
  }
}

// ---------------------------------------------------------------------------
// Fused MLP head: out = relu(H @ Wp1 + bp1) @ Wp2 + bp2, thread-per-node.
// H is fp16 now (halves the 25.6MB round-trip); converted on load, math fp32.
// ---------------------------------------------------------------------------
__global__ __launch_bounds__(256) void mlp_head(const __half* __restrict__ H,
                                                const float* __restrict__ Wp1,
                                                const float* __restrict__ bp1,
                                                const float* __restrict__ Wp2,
                                                const float* __restrict__ bp2,
                                                float* __restrict__ out, int n) {
  __shared__ float W1t[32 * 64];
  __shared__ float w2s[32];
  __shared__ float b1s[32];
  for (int i = threadIdx.x; i < 64 * 32; i += 256) {
    int k = i >> 5, j = i & 31;
    W1t[j * 64 + k] = Wp1[i];
  }
  if (threadIdx.x < 32) {
    w2s[threadIdx.x] = Wp2[threadIdx.x];
    b1s[threadIdx.x] = bp1[threadIdx.x];
  }
  __syncthreads();
  int node = blockIdx.x * 256 + threadIdx.x;
  if (node >= n) return;
  float4 h[16];
  const uint4* __restrict__ hr = (const uint4*)(H + (size_t)node * 64);
#pragma unroll
  for (int j = 0; j < 8; j++) {
    uint4 q = hr[j];
    const __half2* h2 = (const __half2*)&q;
    float2 f0 = __half22float2(h2[0]);
    float2 f1 = __half22float2(h2[1]);
    float2 f2 = __half22float2(h2[2]);
    float2 f3 = __half22float2(h2[3]);
    h[2 * j].x = f0.x; h[2 * j].y = f0.y; h[2 * j].z = f1.x; h[2 * j].w = f1.y;
    h[2 * j + 1].x = f2.x; h[2 * j + 1].y = f2.y;
    h[2 * j + 1].z = f3.x; h[2 * j + 1].w = f3.y;
  }
  float o = bp2[0];
#pragma unroll
  for (int j = 0; j < 32; j++) {
    const float4* wr = (const float4*)(W1t + j * 64);
    float4 a4 = make_float4(0.f, 0.f, 0.f, 0.f);
#pragma unroll
    for (int k = 0; k < 16; k++) {
      float4 w = wr[k];
      a4.x += h[k].x * w.x;
      a4.y += h[k].y * w.y;
      a4.z += h[k].z * w.z;
      a4.w += h[k].w * w.w;
    }
    float a = a4.x + a4.y + a4.z + a4.w + b1s[j];
    a = a > 0.f ? a : 0.f;
    o += a * w2s[j];
  }
  out[node] = o;
}

// ---------------------------------------------------------------------------
extern "C" void kernel_launch(void* const* d_in, const int* in_sizes, int n_in,
                              void* d_out, int out_size, void* d_ws, size_t ws_size,
                              hipStream_t stream) {
  const float* x   = (const float*)d_in[0];
  const int* edge  = (const int*)d_in[1];
  const float* W1  = (const float*)d_in[3];
  const float* b1  = (const float*)d_in[4];
  const float* W2  = (const float*)d_in[5];
  const float* b2  = (const float*)d_in[6];
  const float* W3  = (const float*)d_in[7];
  const float* b3  = (const float*)d_in[8];
  const float* Wp1 = (const float*)d_in[9];
  const float* bp1 = (const float*)d_in[10];
  const float* Wp2 = (const float*)d_in[11];
  const float* bp2 = (const float*)d_in[12];
  float* out = (float*)d_out;

  const int n = in_sizes[0] / NDIM_IN;   // 100000
  const int E = in_sizes[1] / 2;         // 1600000
  const int* src = edge;
  const int* dst = edge + E;

  // workspace carve-out (256B aligned slices)
  char* ws = (char*)d_ws;
  size_t off = 0;
  auto carve = [&](size_t bytes) {
    char* p = ws + off;
    off = (off + bytes + 255) & ~(size_t)255;
    return p;
  };
  int*    histT = (int*)carve((size_t)NB * NC * 4);   // 800 KB (dyn offsets)
  int*    gofs  = (int*)carve(1024 * 4);              // per-bin atomic totals
  int*    bsum  = (int*)carve(1024 * 4);              // scanned bin bases
  int*    tmp   = (int*)carve((size_t)E * 4);         // 6.4 MB (packed)
  int*    col   = (int*)carve((size_t)E * 4);         // 6.4 MB
  int*    rp    = (int*)carve(((size_t)n + 1) * 4);
  float*  dinv  = (float*)carve((size_t)n * 4);
  __half* bufT  = (__half*)carve((size_t)n * HID * 2);
  __half* bufH  = (__half*)carve((size_t)n * HID * 2);
  (void)ws_size; (void)n_in; (void)out_size;

  const int nbN = (n + 255) / 256;        // 391
  const int ntiles = (n + 15) >> 4;       // 6250
  const int nbM = 782;                    // mfma gemm blocks (2 tiles/wave)

  hipMemsetAsync(gofs, 0, NB * 4, stream);
  hist_k<<<NC, 1024, 0, stream>>>(dst, histT, gofs, E);
  scatter_k<<<NC, 1024, 0, stream>>>(src, dst, histT, gofs, bsum, tmp, E);
  binsort_k<<<NB, 256, 0, stream>>>(tmp, bsum, col, rp, dinv, n, E);

  const int nbSp = (n + 31) / 32;         // 8 nodes/wave, 32/block

  // layer 1: 128 -> 64  (fp32 in, fp16 H out)
  gemm_mfma<128, 0><<<nbM, 256, 0, stream>>>(x, W1, dinv, bufT, n, ntiles);
  spmm_relu<<<nbSp, 256, 0, stream>>>(rp, col, bufT, dinv, b1, bufH, n);
  // layer 2: 64 -> 64   (fp16 in, fp16 H out)
  gemm_mfma<64, 1><<<nbM, 256, 0, stream>>>(bufH, W2, dinv, bufT, n, ntiles);
  spmm_relu<<<nbSp, 256, 0, stream>>>(rp, col, bufT, dinv, b2, bufH, n);
  // layer 3: 64 -> 64   (fp16 in, fp16 H out for head)
  gemm_mfma<64, 1><<<nbM, 256, 0, stream>>>(bufH, W3, dinv, bufT, n, ntiles);
  spmm_relu<<<nbSp, 256, 0, stream>>>(rp, col, bufT, dinv, b3, bufH, n);
  // head (fp16 H in)
  mlp_head<<<nbN, 256, 0, stream>>>(bufH, Wp1, bp1, Wp2, bp2, out, n);
}

// Round 10
// 191.873 us; speedup vs baseline: 1.0926x; 1.0926x over previous
//
#include <hip/hip_runtime.h>
#include <hip/hip_bf16.h>
#include <hip/hip_fp16.h>

#define NDIM_IN 128
#define HID 64

#define BINW 128          // dst values per bin
#define NB   782          // ceil(100000/128)
#define NC   256          // phase-1 block count (chunk mapping shared hist/scatter)
#define CAP  3072         // LDS edge buffer per bin (mean 2046, +22 sigma)
#define CAPE 1024         // staged col indices per spmm block (mean 512, +22 sigma)

typedef _Float16 f16x8 __attribute__((ext_vector_type(8)));
typedef float f32x4 __attribute__((ext_vector_type(4)));

// f16-source fused accumulate: acc += f32(f16_half(src)) * 1.0 — bit-identical
// to cvt+add (f16->f32 exact, *1.0 exact), 1 VALU inst instead of 2.
// NOTE: macro params must NOT be named x/y/z/w — the preprocessor substitutes
// member-name tokens too (R7 compile failure).
#define MIX_LO(acc, hsrc) \
  asm("v_fma_mix_f32 %0, %1, %2, %0 op_sel:[0,0,0] op_sel_hi:[1,0,0]" \
      : "+v"(acc) : "v"(hsrc), "v"(one))
#define MIX_HI(acc, hsrc) \
  asm("v_fma_mix_f32 %0, %1, %2, %0 op_sel:[1,0,0] op_sel_hi:[1,0,0]" \
      : "+v"(acc) : "v"(hsrc), "v"(one))
#define ACC8(a, q) do { \
  MIX_LO(a[0], (q).x); MIX_HI(a[1], (q).x); \
  MIX_LO(a[2], (q).y); MIX_HI(a[3], (q).y); \
  MIX_LO(a[4], (q).z); MIX_HI(a[5], (q).z); \
  MIX_LO(a[6], (q).w); MIX_HI(a[7], (q).w); } while (0)

// ---------------------------------------------------------------------------
// Phase 1a: per-block LDS histogram over bins + DYNAMIC within-bin range
// reservation via atomicAdd(&gofs[bin], h[bin]) (replaces scan1 — R9 win).
// gofs zeroed by memsetAsync; final value = per-bin total for scatter's scan.
// ---------------------------------------------------------------------------
__global__ __launch_bounds__(1024) void hist_k(const int* __restrict__ dst,
                                               int* __restrict__ histT,
                                               int* __restrict__ gofs, int E) {
  __shared__ int h[NB];
  for (int i = threadIdx.x; i < NB; i += 1024) h[i] = 0;
  __syncthreads();
  int E4 = E >> 2;
  int chunk = (E4 + NC - 1) / NC;
  int beg = blockIdx.x * chunk;
  int end = min(E4, beg + chunk);
  const int4* __restrict__ d4 = (const int4*)dst;
  for (int i = beg + (int)threadIdx.x; i < end; i += 1024) {
    int4 d = d4[i];
    atomicAdd(&h[d.x >> 7], 1);
    atomicAdd(&h[d.y >> 7], 1);
    atomicAdd(&h[d.z >> 7], 1);
    atomicAdd(&h[d.w >> 7], 1);
  }
  __syncthreads();
  for (int i = threadIdx.x; i < NB; i += 1024) {
    int c = h[i];
    int ofs = atomicAdd(&gofs[i], c);     // reserve range within bin
    histT[i * NC + blockIdx.x] = ofs;     // this block's within-bin offset
  }
}

// ---------------------------------------------------------------------------
// Phase 1c: scatter packed (src<<7 | dst&127) into tmp, grouped by bin.
// LDS scan of gofs (782 totals) -> bin bases; block 0 publishes to bsum_out.
// ---------------------------------------------------------------------------
__global__ __launch_bounds__(1024) void scatter_k(const int* __restrict__ src,
                                                  const int* __restrict__ dst,
                                                  const int* __restrict__ S,
                                                  const int* __restrict__ gofs,
                                                  int* __restrict__ bsum_out,
                                                  int* __restrict__ tmp, int E) {
  __shared__ int cur[NB];
  __shared__ int sc[1024];
  int t = threadIdx.x;
  int v = (t < NB) ? gofs[t] : 0;
  sc[t] = v;
  __syncthreads();
  for (int off = 1; off < 1024; off <<= 1) {
    int x = (t >= off) ? sc[t - off] : 0;
    __syncthreads();
    sc[t] += x;
    __syncthreads();
  }
  if (t < NB) {
    int ex = sc[t] - v;                       // exclusive bin base
    cur[t] = S[t * NC + blockIdx.x] + ex;
    if (blockIdx.x == 0) bsum_out[t] = ex;    // publish for binsort_k
  }
  __syncthreads();
  int E4 = E >> 2;
  int chunk = (E4 + NC - 1) / NC;
  int beg = blockIdx.x * chunk;
  int end = min(E4, beg + chunk);
  const int4* __restrict__ d4 = (const int4*)dst;
  const int4* __restrict__ s4 = (const int4*)src;
  for (int i = beg + (int)threadIdx.x; i < end; i += 1024) {
    int4 d = d4[i];
    int4 sv = s4[i];
    int p0 = atomicAdd(&cur[d.x >> 7], 1); tmp[p0] = (sv.x << 7) | (d.x & 127);
    int p1 = atomicAdd(&cur[d.y >> 7], 1); tmp[p1] = (sv.y << 7) | (d.y & 127);
    int p2 = atomicAdd(&cur[d.z >> 7], 1); tmp[p2] = (sv.z << 7) | (d.z & 127);
    int p3 = atomicAdd(&cur[d.w >> 7], 1); tmp[p3] = (sv.w << 7) | (d.w & 127);
  }
}

// ---------------------------------------------------------------------------
// Phase 2: one block per bin; in-LDS counting sort -> col, rp, dinv.
// ---------------------------------------------------------------------------
__global__ __launch_bounds__(256) void binsort_k(const int* __restrict__ tmp,
                                                 const int* __restrict__ bsum,
                                                 int* __restrict__ col,
                                                 int* __restrict__ rp,
                                                 float* __restrict__ dinv,
                                                 int n, int E) {
  int bin = blockIdx.x;
  int base = bsum[bin];
  int end = (bin == NB - 1) ? E : bsum[bin + 1];
  int m = end - base;
  __shared__ int cnt[BINW];
  __shared__ int offs[BINW];
  __shared__ int cur[BINW];
  __shared__ int buf[CAP];
  int t = threadIdx.x;
  if (t < BINW) cnt[t] = 0;
  __syncthreads();
  for (int i = t; i < m; i += 256) {
    int p = tmp[base + i];
    atomicAdd(&cnt[p & (BINW - 1)], 1);
  }
  __syncthreads();
  if (t < BINW) offs[t] = cnt[t];
  __syncthreads();
  for (int off = 1; off < BINW; off <<= 1) {
    int x = (t < BINW && t >= off) ? offs[t - off] : 0;
    __syncthreads();
    if (t < BINW) offs[t] += x;
    __syncthreads();
  }
  if (t < BINW) {
    int ex = offs[t] - cnt[t];
    cur[t] = ex;
    int v = bin * BINW + t;
    if (v < n) {
      rp[v] = base + ex;
      dinv[v] = rsqrtf((float)cnt[t] + 1.0f);  // +1 = self loop
    }
  }
  if (bin == NB - 1 && t == 0) rp[n] = E;
  __syncthreads();
  for (int i = t; i < m; i += 256) {
    int p = tmp[base + i];
    int r = atomicAdd(&cur[p & (BINW - 1)], 1);
    if (r < CAP) buf[r] = p >> 7;
  }
  __syncthreads();
  int mm = min(m, CAP);
  for (int i = t; i < mm; i += 256) col[base + i] = buf[i];
}

// ---------------------------------------------------------------------------
// MFMA dense transform: T' = (X @ W) * dinv[row], output fp16.
// FP16IN=1: input rows already fp16 (inter-layer H) -> direct f16x8 loads.
// Layouts (verified m89/m91/m120): A[m=lane&15][k=quad*8+j],
// B[k=quad*8+j][n=lane&15], D[row=quad*4+r][col=lane&15].
// ---------------------------------------------------------------------------
template <int K, int FP16IN>
__global__ __launch_bounds__(256) void gemm_mfma(const void* __restrict__ Xv,
                                                 const float* __restrict__ W,
                                                 const float* __restrict__ dinv,
                                                 __half* __restrict__ T,
                                                 int n, int ntiles) {
  constexpr int NCH = K / 32;
  __shared__ float Ds[4][16 * 68];
  int wv = threadIdx.x >> 6;
  int lane = threadIdx.x & 63;
  int colx = lane & 15;
  int quad = lane >> 4;

  // B fragments: whole W, fp16, stationary
  f16x8 bf[4][NCH];
#pragma unroll
  for (int t = 0; t < 4; t++)
#pragma unroll
    for (int c = 0; c < NCH; c++) {
      f16x8 b;
#pragma unroll
      for (int j = 0; j < 8; j++)
        b[j] = (_Float16)W[(32 * c + quad * 8 + j) * 64 + 16 * t + colx];
      bf[t][c] = b;
    }

  for (int tile = blockIdx.x * 4 + wv; tile < ntiles; tile += gridDim.x * 4) {
    int node0 = tile * 16;
    f32x4 acc[4] = {{0.f, 0.f, 0.f, 0.f}, {0.f, 0.f, 0.f, 0.f},
                    {0.f, 0.f, 0.f, 0.f}, {0.f, 0.f, 0.f, 0.f}};
    int arow = min(node0 + colx, n - 1);
#pragma unroll
    for (int c = 0; c < NCH; c++) {
      f16x8 a;
      if constexpr (FP16IN) {
        const _Float16* __restrict__ xr = (const _Float16*)Xv + (size_t)arow * K;
        a = *(const f16x8*)(xr + 32 * c + quad * 8);
      } else {
        const float* __restrict__ xr = (const float*)Xv + (size_t)arow * K;
        float4 x0 = *(const float4*)(xr + 32 * c + quad * 8);
        float4 x1 = *(const float4*)(xr + 32 * c + quad * 8 + 4);
        a[0] = (_Float16)x0.x; a[1] = (_Float16)x0.y;
        a[2] = (_Float16)x0.z; a[3] = (_Float16)x0.w;
        a[4] = (_Float16)x1.x; a[5] = (_Float16)x1.y;
        a[6] = (_Float16)x1.z; a[7] = (_Float16)x1.w;
      }
#pragma unroll
      for (int t = 0; t < 4; t++)
        acc[t] = __builtin_amdgcn_mfma_f32_16x16x32_f16(a, bf[t][c], acc[t], 0, 0, 0);
    }
    // epilogue: scale rows by dinv, transpose through LDS, emit fp16
    float dv[4];
#pragma unroll
    for (int r = 0; r < 4; r++) {
      int nd = min(node0 + quad * 4 + r, n - 1);
      dv[r] = dinv[nd];
    }
#pragma unroll
    for (int t = 0; t < 4; t++)
#pragma unroll
      for (int r = 0; r < 4; r++)
        Ds[wv][(quad * 4 + r) * 68 + 16 * t + colx] = acc[t][r] * dv[r];
    int nd = node0 + colx;
    const float* __restrict__ row = &Ds[wv][colx * 68 + quad * 16];
    float4 y0 = *(const float4*)(row + 0);
    float4 y1 = *(const float4*)(row + 4);
    float4 y2 = *(const float4*)(row + 8);
    float4 y3 = *(const float4*)(row + 12);
    f16x8 o0, o1;
    o0[0] = (_Float16)y0.x; o0[1] = (_Float16)y0.y;
    o0[2] = (_Float16)y0.z; o0[3] = (_Float16)y0.w;
    o0[4] = (_Float16)y1.x; o0[5] = (_Float16)y1.y;
    o0[6] = (_Float16)y1.z; o0[7] = (_Float16)y1.w;
    o1[0] = (_Float16)y2.x; o1[1] = (_Float16)y2.y;
    o1[2] = (_Float16)y2.z; o1[3] = (_Float16)y2.w;
    o1[4] = (_Float16)y3.x; o1[5] = (_Float16)y3.y;
    o1[6] = (_Float16)y3.z; o1[7] = (_Float16)y3.w;
    if (nd < n) {
      uint4* __restrict__ o = (uint4*)(T + (size_t)nd * 64 + quad * 16);
      o[0] = *(uint4*)&o0;
      o[1] = *(uint4*)&o1;
    }
  }
}

// ---------------------------------------------------------------------------
// SpMM gather: GROUP-per-node, LDS-staged col indices (R5), 8-edge unroll
// (R9-verified win: 8 independent col->T chains hide Infinity-Cache latency),
// 2 accumulator sets, v_fma_mix.
// MODE 0: emit fp16 H.  MODE 1: emit fp32 H (layer 3, for mlp_head — R9
// lesson: the fp16-input head spills to scratch, keep head input fp32).
// NOTE R3 lesson: do NOT fuse the MLP head here (VGPR/LDS kill occupancy).
// ---------------------------------------------------------------------------
template <int MODE>
__global__ __launch_bounds__(256) void spmm_relu(const int* __restrict__ rp,
                                                 const int* __restrict__ col,
                                                 const __half* __restrict__ T,
                                                 const float* __restrict__ dinv,
                                                 const float* __restrict__ bias,
                                                 void* __restrict__ Hout, int n) {
  __shared__ int colS[CAPE];
  int v0 = blockIdx.x * 32;
  int ebeg = rp[v0];
  int eend = rp[min(v0 + 32, n)];
  int m = eend - ebeg;
  int mstage = min(m, CAPE);
  for (int i = threadIdx.x; i < mstage; i += 256) colS[i] = col[ebeg + i];
  __syncthreads();

  int lane = threadIdx.x & 63;
  int wv = threadIdx.x >> 6;
  int g = lane >> 3;
  int sub = lane & 7;
  int v = v0 + wv * 8 + g;
  bool valid = v < n;
  if (!valid) v = n - 1;
  const uint4* __restrict__ T8 = (const uint4*)T;
  int beg = rp[v];
  int end = rp[v + 1];
  int lim = min(end, ebeg + CAPE);   // staged portion of this node's edges

  float one = 1.0f;
  float a0[8], a1[8];
#pragma unroll
  for (int j = 0; j < 8; j++) { a0[j] = 0.f; a1[j] = 0.f; }
  // self-loop row (every group loads its own node's row slice)
  {
    uint4 q0 = T8[(size_t)v * 8 + sub];
    ACC8(a0, q0);
  }
  int e = beg;
  for (; e + 8 <= lim; e += 8) {
    int s0 = colS[e - ebeg];
    int s1 = colS[e - ebeg + 1];
    int s2 = colS[e - ebeg + 2];
    int s3 = colS[e - ebeg + 3];
    int s4 = colS[e - ebeg + 4];
    int s5 = colS[e - ebeg + 5];
    int s6 = colS[e - ebeg + 6];
    int s7 = colS[e - ebeg + 7];
    uint4 q0 = T8[(size_t)s0 * 8 + sub];
    uint4 q1 = T8[(size_t)s1 * 8 + sub];
    uint4 q2 = T8[(size_t)s2 * 8 + sub];
    uint4 q3 = T8[(size_t)s3 * 8 + sub];
    uint4 q4 = T8[(size_t)s4 * 8 + sub];
    uint4 q5 = T8[(size_t)s5 * 8 + sub];
    uint4 q6 = T8[(size_t)s6 * 8 + sub];
    uint4 q7 = T8[(size_t)s7 * 8 + sub];
    ACC8(a0, q0);
    ACC8(a1, q1);
    ACC8(a0, q2);
    ACC8(a1, q3);
    ACC8(a0, q4);
    ACC8(a1, q5);
    ACC8(a0, q6);
    ACC8(a1, q7);
  }
  for (; e + 4 <= lim; e += 4) {
    int s0 = colS[e - ebeg];
    int s1 = colS[e - ebeg + 1];
    int s2 = colS[e - ebeg + 2];
    int s3 = colS[e - ebeg + 3];
    uint4 q0 = T8[(size_t)s0 * 8 + sub];
    uint4 q1 = T8[(size_t)s1 * 8 + sub];
    uint4 q2 = T8[(size_t)s2 * 8 + sub];
    uint4 q3 = T8[(size_t)s3 * 8 + sub];
    ACC8(a0, q0);
    ACC8(a1, q1);
    ACC8(a0, q2);
    ACC8(a1, q3);
  }
  for (; e < lim; ++e) {
    int s0 = colS[e - ebeg];
    uint4 q0 = T8[(size_t)s0 * 8 + sub];
    ACC8(a0, q0);
  }
  // overflow fallback (cold; only if block range exceeded CAPE)
  for (; e < end; ++e) {
    int s0 = col[e];
    uint4 q0 = T8[(size_t)s0 * 8 + sub];
    ACC8(a0, q0);
  }
  float di = dinv[v];
  const float4* __restrict__ b4 = (const float4*)bias;
  float4 bA = b4[sub * 2], bB = b4[sub * 2 + 1];
  float4 rA, rB;
  rA.x = di * (a0[0] + a1[0]) + bA.x;
  rA.y = di * (a0[1] + a1[1]) + bA.y;
  rA.z = di * (a0[2] + a1[2]) + bA.z;
  rA.w = di * (a0[3] + a1[3]) + bA.w;
  rB.x = di * (a0[4] + a1[4]) + bB.x;
  rB.y = di * (a0[5] + a1[5]) + bB.y;
  rB.z = di * (a0[6] + a1[6]) + bB.z;
  rB.w = di * (a0[7] + a1[7]) + bB.w;
  rA.x = rA.x > 0.f ? rA.x : 0.f;  rA.y = rA.y > 0.f ? rA.y : 0.f;
  rA.z = rA.z > 0.f ? rA.z : 0.f;  rA.w = rA.w > 0.f ? rA.w : 0.f;
  rB.x = rB.x > 0.f ? rB.x : 0.f;  rB.y = rB.y > 0.f ? rB.y : 0.f;
  rB.z = rB.z > 0.f ? rB.z : 0.f;  rB.w = rB.w > 0.f ? rB.w : 0.f;
  if (valid) {
    if constexpr (MODE == 0) {
      f16x8 o;
      o[0] = (_Float16)rA.x; o[1] = (_Float16)rA.y;
      o[2] = (_Float16)rA.z; o[3] = (_Float16)rA.w;
      o[4] = (_Float16)rB.x; o[5] = (_Float16)rB.y;
      o[6] = (_Float16)rB.z; o[7] = (_Float16)rB.w;
      uint4* __restrict__ o4 = (uint4*)((__half*)Hout + (size_t)v * HID + sub * 8);
      *o4 = *(uint4*)&o;
    } else {
      float4* __restrict__ o = (float4*)((float*)Hout + (size_t)v * HID + sub * 8);
      o[0] = rA;
      o[1] = rB;
    }
  }
}

// ---------------------------------------------------------------------------
// Fused MLP head: out = relu(H @ Wp1 + bp1) @ Wp2 + bp2, thread-per-node.
// fp32 H input — R9 lesson: the fp16-load variant (uint4 + (__half2*)&local)
// spilled h[16] to scratch (VGPR 256, 10.7MB writes, 47us). This exact fp32
// version is measured-good (~5us).
// ---------------------------------------------------------------------------
__global__ __launch_bounds__(256) void mlp_head(const float* __restrict__ H,
                                                const float* __restrict__ Wp1,
                                                const float* __restrict__ bp1,
                                                const float* __restrict__ Wp2,
                                                const float* __restrict__ bp2,
                                                float* __restrict__ out, int n) {
  __shared__ float W1t[32 * 64];
  __shared__ float w2s[32];
  __shared__ float b1s[32];
  for (int i = threadIdx.x; i < 64 * 32; i += 256) {
    int k = i >> 5, j = i & 31;
    W1t[j * 64 + k] = Wp1[i];
  }
  if (threadIdx.x < 32) {
    w2s[threadIdx.x] = Wp2[threadIdx.x];
    b1s[threadIdx.x] = bp1[threadIdx.x];
  }
  __syncthreads();
  int node = blockIdx.x * 256 + threadIdx.x;
  if (node >= n) return;
  float4 h[16];
  const float4* __restrict__ hr = (const float4*)(H + (size_t)node * 64);
#pragma unroll
  for (int j = 0; j < 16; j++) h[j] = hr[j];
  float o = bp2[0];
#pragma unroll
  for (int j = 0; j < 32; j++) {
    const float4* wr = (const float4*)(W1t + j * 64);
    float4 a4 = make_float4(0.f, 0.f, 0.f, 0.f);
#pragma unroll
    for (int k = 0; k < 16; k++) {
      float4 w = wr[k];
      a4.x += h[k].x * w.x;
      a4.y += h[k].y * w.y;
      a4.z += h[k].z * w.z;
      a4.w += h[k].w * w.w;
    }
    float a = a4.x + a4.y + a4.z + a4.w + b1s[j];
    a = a > 0.f ? a : 0.f;
    o += a * w2s[j];
  }
  out[node] = o;
}

// ---------------------------------------------------------------------------
extern "C" void kernel_launch(void* const* d_in, const int* in_sizes, int n_in,
                              void* d_out, int out_size, void* d_ws, size_t ws_size,
                              hipStream_t stream) {
  const float* x   = (const float*)d_in[0];
  const int* edge  = (const int*)d_in[1];
  const float* W1  = (const float*)d_in[3];
  const float* b1  = (const float*)d_in[4];
  const float* W2  = (const float*)d_in[5];
  const float* b2  = (const float*)d_in[6];
  const float* W3  = (const float*)d_in[7];
  const float* b3  = (const float*)d_in[8];
  const float* Wp1 = (const float*)d_in[9];
  const float* bp1 = (const float*)d_in[10];
  const float* Wp2 = (const float*)d_in[11];
  const float* bp2 = (const float*)d_in[12];
  float* out = (float*)d_out;

  const int n = in_sizes[0] / NDIM_IN;   // 100000
  const int E = in_sizes[1] / 2;         // 1600000
  const int* src = edge;
  const int* dst = edge + E;

  // workspace carve-out (256B aligned slices)
  char* ws = (char*)d_ws;
  size_t off = 0;
  auto carve = [&](size_t bytes) {
    char* p = ws + off;
    off = (off + bytes + 255) & ~(size_t)255;
    return p;
  };
  int*    histT = (int*)carve((size_t)NB * NC * 4);   // 800 KB (dyn offsets)
  int*    gofs  = (int*)carve(1024 * 4);              // per-bin atomic totals
  int*    bsum  = (int*)carve(1024 * 4);              // scanned bin bases
  int*    tmp   = (int*)carve((size_t)E * 4);         // 6.4 MB (packed)
  int*    col   = (int*)carve((size_t)E * 4);         // 6.4 MB
  int*    rp    = (int*)carve(((size_t)n + 1) * 4);
  float*  dinv  = (float*)carve((size_t)n * 4);
  __half* bufT  = (__half*)carve((size_t)n * HID * 2);
  float*  bufA  = (float*)carve((size_t)n * HID * 4);  // fp32 H (layer 3 only)
  __half* bufH  = (__half*)bufA;  // fp16 H (layers 1-2); lifetime disjoint w/ bufA
  (void)ws_size; (void)n_in; (void)out_size;

  const int nbN = (n + 255) / 256;        // 391
  const int ntiles = (n + 15) >> 4;       // 6250
  const int nbM = 782;                    // mfma gemm blocks (2 tiles/wave)

  hipMemsetAsync(gofs, 0, NB * 4, stream);
  hist_k<<<NC, 1024, 0, stream>>>(dst, histT, gofs, E);
  scatter_k<<<NC, 1024, 0, stream>>>(src, dst, histT, gofs, bsum, tmp, E);
  binsort_k<<<NB, 256, 0, stream>>>(tmp, bsum, col, rp, dinv, n, E);

  const int nbSp = (n + 31) / 32;         // 8 nodes/wave, 32/block

  // layer 1: 128 -> 64  (fp32 in, fp16 H out)
  gemm_mfma<128, 0><<<nbM, 256, 0, stream>>>(x, W1, dinv, bufT, n, ntiles);
  spmm_relu<0><<<nbSp, 256, 0, stream>>>(rp, col, bufT, dinv, b1, bufH, n);
  // layer 2: 64 -> 64   (fp16 in, fp16 H out)
  gemm_mfma<64, 1><<<nbM, 256, 0, stream>>>(bufH, W2, dinv, bufT, n, ntiles);
  spmm_relu<0><<<nbSp, 256, 0, stream>>>(rp, col, bufT, dinv, b2, bufH, n);
  // layer 3: 64 -> 64   (fp16 in, fp32 H out for head)
  gemm_mfma<64, 1><<<nbM, 256, 0, stream>>>(bufH, W3, dinv, bufT, n, ntiles);
  spmm_relu<1><<<nbSp, 256, 0, stream>>>(rp, col, bufT, dinv, b3, bufA, n);
  // head (fp32 H in — measured-good)
  mlp_head<<<nbN, 256, 0, stream>>>(bufA, Wp1, bp1, Wp2, bp2, out, n);
}

// Round 11
// 189.493 us; speedup vs baseline: 1.1064x; 1.0126x over previous
//
#include <hip/hip_runtime.h>
#include <hip/hip_bf16.h>
#include <hip/hip_fp16.h>

#define NDIM_IN 128
#define HID 64

#define BINW 128          // dst values per bin
#define NB   782          // ceil(100000/128)
#define NC   256          // phase-1 block count (chunk mapping shared hist/scatter)
#define CAP  3072         // LDS edge buffer per bin (mean 2046, +22 sigma)
#define CAPE 1024         // staged col indices per spmm block (mean 512, +22 sigma)

typedef _Float16 f16x8 __attribute__((ext_vector_type(8)));
typedef float f32x4 __attribute__((ext_vector_type(4)));

// f16-source fused accumulate: acc += f32(f16_half(src)) * 1.0 — bit-identical
// to cvt+add (f16->f32 exact, *1.0 exact), 1 VALU inst instead of 2.
// NOTE: macro params must NOT be named x/y/z/w — the preprocessor substitutes
// member-name tokens too (R7 compile failure).
#define MIX_LO(acc, hsrc) \
  asm("v_fma_mix_f32 %0, %1, %2, %0 op_sel:[0,0,0] op_sel_hi:[1,0,0]" \
      : "+v"(acc) : "v"(hsrc), "v"(one))
#define MIX_HI(acc, hsrc) \
  asm("v_fma_mix_f32 %0, %1, %2, %0 op_sel:[1,0,0] op_sel_hi:[1,0,0]" \
      : "+v"(acc) : "v"(hsrc), "v"(one))
#define ACC8(a, q) do { \
  MIX_LO(a[0], (q).x); MIX_HI(a[1], (q).x); \
  MIX_LO(a[2], (q).y); MIX_HI(a[3], (q).y); \
  MIX_LO(a[4], (q).z); MIX_HI(a[5], (q).z); \
  MIX_LO(a[6], (q).w); MIX_HI(a[7], (q).w); } while (0)

// ---------------------------------------------------------------------------
// Phase 1a: per-block LDS histogram over bins + DYNAMIC within-bin range
// reservation via atomicAdd(&gofs[bin], h[bin]) (replaces scan1).
// gofs zeroed by memsetAsync; final value = per-bin total for scatter's scan.
// ---------------------------------------------------------------------------
__global__ __launch_bounds__(1024) void hist_k(const int* __restrict__ dst,
                                               int* __restrict__ histT,
                                               int* __restrict__ gofs, int E) {
  __shared__ int h[NB];
  for (int i = threadIdx.x; i < NB; i += 1024) h[i] = 0;
  __syncthreads();
  int E4 = E >> 2;
  int chunk = (E4 + NC - 1) / NC;
  int beg = blockIdx.x * chunk;
  int end = min(E4, beg + chunk);
  const int4* __restrict__ d4 = (const int4*)dst;
  for (int i = beg + (int)threadIdx.x; i < end; i += 1024) {
    int4 d = d4[i];
    atomicAdd(&h[d.x >> 7], 1);
    atomicAdd(&h[d.y >> 7], 1);
    atomicAdd(&h[d.z >> 7], 1);
    atomicAdd(&h[d.w >> 7], 1);
  }
  __syncthreads();
  for (int i = threadIdx.x; i < NB; i += 1024) {
    int c = h[i];
    int ofs = atomicAdd(&gofs[i], c);     // reserve range within bin
    histT[i * NC + blockIdx.x] = ofs;     // this block's within-bin offset
  }
}

// ---------------------------------------------------------------------------
// Phase 1c: scatter packed (src<<7 | dst&127) into tmp, grouped by bin.
// LDS scan of gofs (782 totals) -> bin bases; block 0 publishes to bsum_out.
// ---------------------------------------------------------------------------
__global__ __launch_bounds__(1024) void scatter_k(const int* __restrict__ src,
                                                  const int* __restrict__ dst,
                                                  const int* __restrict__ S,
                                                  const int* __restrict__ gofs,
                                                  int* __restrict__ bsum_out,
                                                  int* __restrict__ tmp, int E) {
  __shared__ int cur[NB];
  __shared__ int sc[1024];
  int t = threadIdx.x;
  int v = (t < NB) ? gofs[t] : 0;
  sc[t] = v;
  __syncthreads();
  for (int off = 1; off < 1024; off <<= 1) {
    int x = (t >= off) ? sc[t - off] : 0;
    __syncthreads();
    sc[t] += x;
    __syncthreads();
  }
  if (t < NB) {
    int ex = sc[t] - v;                       // exclusive bin base
    cur[t] = S[t * NC + blockIdx.x] + ex;
    if (blockIdx.x == 0) bsum_out[t] = ex;    // publish for binsort_k
  }
  __syncthreads();
  int E4 = E >> 2;
  int chunk = (E4 + NC - 1) / NC;
  int beg = blockIdx.x * chunk;
  int end = min(E4, beg + chunk);
  const int4* __restrict__ d4 = (const int4*)dst;
  const int4* __restrict__ s4 = (const int4*)src;
  for (int i = beg + (int)threadIdx.x; i < end; i += 1024) {
    int4 d = d4[i];
    int4 sv = s4[i];
    int p0 = atomicAdd(&cur[d.x >> 7], 1); tmp[p0] = (sv.x << 7) | (d.x & 127);
    int p1 = atomicAdd(&cur[d.y >> 7], 1); tmp[p1] = (sv.y << 7) | (d.y & 127);
    int p2 = atomicAdd(&cur[d.z >> 7], 1); tmp[p2] = (sv.z << 7) | (d.z & 127);
    int p3 = atomicAdd(&cur[d.w >> 7], 1); tmp[p3] = (sv.w << 7) | (d.w & 127);
  }
}

// ---------------------------------------------------------------------------
// Phase 2: one block per bin; in-LDS counting sort -> col, rp, dinv.
// ---------------------------------------------------------------------------
__global__ __launch_bounds__(256) void binsort_k(const int* __restrict__ tmp,
                                                 const int* __restrict__ bsum,
                                                 int* __restrict__ col,
                                                 int* __restrict__ rp,
                                                 float* __restrict__ dinv,
                                                 int n, int E) {
  int bin = blockIdx.x;
  int base = bsum[bin];
  int end = (bin == NB - 1) ? E : bsum[bin + 1];
  int m = end - base;
  __shared__ int cnt[BINW];
  __shared__ int offs[BINW];
  __shared__ int cur[BINW];
  __shared__ int buf[CAP];
  int t = threadIdx.x;
  if (t < BINW) cnt[t] = 0;
  __syncthreads();
  for (int i = t; i < m; i += 256) {
    int p = tmp[base + i];
    atomicAdd(&cnt[p & (BINW - 1)], 1);
  }
  __syncthreads();
  if (t < BINW) offs[t] = cnt[t];
  __syncthreads();
  for (int off = 1; off < BINW; off <<= 1) {
    int x = (t < BINW && t >= off) ? offs[t - off] : 0;
    __syncthreads();
    if (t < BINW) offs[t] += x;
    __syncthreads();
  }
  if (t < BINW) {
    int ex = offs[t] - cnt[t];
    cur[t] = ex;
    int v = bin * BINW + t;
    if (v < n) {
      rp[v] = base + ex;
      dinv[v] = rsqrtf((float)cnt[t] + 1.0f);  // +1 = self loop
    }
  }
  if (bin == NB - 1 && t == 0) rp[n] = E;
  __syncthreads();
  for (int i = t; i < m; i += 256) {
    int p = tmp[base + i];
    int r = atomicAdd(&cur[p & (BINW - 1)], 1);
    if (r < CAP) buf[r] = p >> 7;
  }
  __syncthreads();
  int mm = min(m, CAP);
  for (int i = t; i < mm; i += 256) col[base + i] = buf[i];
}

// ---------------------------------------------------------------------------
// MFMA dense transform: T' = (X @ W) * dinv[row], output fp16.
// FP16IN=1: input rows already fp16 (inter-layer H) -> direct f16x8 loads.
// Layouts (verified m89/m91/m120): A[m=lane&15][k=quad*8+j],
// B[k=quad*8+j][n=lane&15], D[row=quad*4+r][col=lane&15].
// ---------------------------------------------------------------------------
template <int K, int FP16IN>
__global__ __launch_bounds__(256) void gemm_mfma(const void* __restrict__ Xv,
                                                 const float* __restrict__ W,
                                                 const float* __restrict__ dinv,
                                                 __half* __restrict__ T,
                                                 int n, int ntiles) {
  constexpr int NCH = K / 32;
  __shared__ float Ds[4][16 * 68];
  int wv = threadIdx.x >> 6;
  int lane = threadIdx.x & 63;
  int colx = lane & 15;
  int quad = lane >> 4;

  // B fragments: whole W, fp16, stationary
  f16x8 bf[4][NCH];
#pragma unroll
  for (int t = 0; t < 4; t++)
#pragma unroll
    for (int c = 0; c < NCH; c++) {
      f16x8 b;
#pragma unroll
      for (int j = 0; j < 8; j++)
        b[j] = (_Float16)W[(32 * c + quad * 8 + j) * 64 + 16 * t + colx];
      bf[t][c] = b;
    }

  for (int tile = blockIdx.x * 4 + wv; tile < ntiles; tile += gridDim.x * 4) {
    int node0 = tile * 16;
    f32x4 acc[4] = {{0.f, 0.f, 0.f, 0.f}, {0.f, 0.f, 0.f, 0.f},
                    {0.f, 0.f, 0.f, 0.f}, {0.f, 0.f, 0.f, 0.f}};
    int arow = min(node0 + colx, n - 1);
#pragma unroll
    for (int c = 0; c < NCH; c++) {
      f16x8 a;
      if constexpr (FP16IN) {
        const _Float16* __restrict__ xr = (const _Float16*)Xv + (size_t)arow * K;
        a = *(const f16x8*)(xr + 32 * c + quad * 8);
      } else {
        const float* __restrict__ xr = (const float*)Xv + (size_t)arow * K;
        float4 x0 = *(const float4*)(xr + 32 * c + quad * 8);
        float4 x1 = *(const float4*)(xr + 32 * c + quad * 8 + 4);
        a[0] = (_Float16)x0.x; a[1] = (_Float16)x0.y;
        a[2] = (_Float16)x0.z; a[3] = (_Float16)x0.w;
        a[4] = (_Float16)x1.x; a[5] = (_Float16)x1.y;
        a[6] = (_Float16)x1.z; a[7] = (_Float16)x1.w;
      }
#pragma unroll
      for (int t = 0; t < 4; t++)
        acc[t] = __builtin_amdgcn_mfma_f32_16x16x32_f16(a, bf[t][c], acc[t], 0, 0, 0);
    }
    // epilogue: scale rows by dinv, transpose through LDS, emit fp16
    float dv[4];
#pragma unroll
    for (int r = 0; r < 4; r++) {
      int nd = min(node0 + quad * 4 + r, n - 1);
      dv[r] = dinv[nd];
    }
#pragma unroll
    for (int t = 0; t < 4; t++)
#pragma unroll
      for (int r = 0; r < 4; r++)
        Ds[wv][(quad * 4 + r) * 68 + 16 * t + colx] = acc[t][r] * dv[r];
    int nd = node0 + colx;
    const float* __restrict__ row = &Ds[wv][colx * 68 + quad * 16];
    float4 y0 = *(const float4*)(row + 0);
    float4 y1 = *(const float4*)(row + 4);
    float4 y2 = *(const float4*)(row + 8);
    float4 y3 = *(const float4*)(row + 12);
    f16x8 o0, o1;
    o0[0] = (_Float16)y0.x; o0[1] = (_Float16)y0.y;
    o0[2] = (_Float16)y0.z; o0[3] = (_Float16)y0.w;
    o0[4] = (_Float16)y1.x; o0[5] = (_Float16)y1.y;
    o0[6] = (_Float16)y1.z; o0[7] = (_Float16)y1.w;
    o1[0] = (_Float16)y2.x; o1[1] = (_Float16)y2.y;
    o1[2] = (_Float16)y2.z; o1[3] = (_Float16)y2.w;
    o1[4] = (_Float16)y3.x; o1[5] = (_Float16)y3.y;
    o1[6] = (_Float16)y3.z; o1[7] = (_Float16)y3.w;
    if (nd < n) {
      uint4* __restrict__ o = (uint4*)(T + (size_t)nd * 64 + quad * 16);
      o[0] = *(uint4*)&o0;
      o[1] = *(uint4*)&o1;
    }
  }
}

// ---------------------------------------------------------------------------
// SpMM gather: GROUP-per-node, LDS-staged col indices (R5), 4-edge unroll
// with 2 accumulator sets (R8-measured best; R10 lesson: 8-edge unroll
// crosses the 64-VGPR occupancy cliff — waves/SIMD halve — net loss for
// this latency-bound gather), v_fma_mix accumulate.
// MODE 0: emit fp16 H.  MODE 1: emit fp32 H (layer 3, for mlp_head — R9
// lesson: the fp16-input head spills to scratch, keep head input fp32).
// NOTE R3 lesson: do NOT fuse the MLP head here (VGPR/LDS kill occupancy).
// ---------------------------------------------------------------------------
template <int MODE>
__global__ __launch_bounds__(256) void spmm_relu(const int* __restrict__ rp,
                                                 const int* __restrict__ col,
                                                 const __half* __restrict__ T,
                                                 const float* __restrict__ dinv,
                                                 const float* __restrict__ bias,
                                                 void* __restrict__ Hout, int n) {
  __shared__ int colS[CAPE];
  int v0 = blockIdx.x * 32;
  int ebeg = rp[v0];
  int eend = rp[min(v0 + 32, n)];
  int m = eend - ebeg;
  int mstage = min(m, CAPE);
  for (int i = threadIdx.x; i < mstage; i += 256) colS[i] = col[ebeg + i];
  __syncthreads();

  int lane = threadIdx.x & 63;
  int wv = threadIdx.x >> 6;
  int g = lane >> 3;
  int sub = lane & 7;
  int v = v0 + wv * 8 + g;
  bool valid = v < n;
  if (!valid) v = n - 1;
  const uint4* __restrict__ T8 = (const uint4*)T;
  int beg = rp[v];
  int end = rp[v + 1];
  int lim = min(end, ebeg + CAPE);   // staged portion of this node's edges

  float one = 1.0f;
  float a0[8], a1[8];
#pragma unroll
  for (int j = 0; j < 8; j++) { a0[j] = 0.f; a1[j] = 0.f; }
  // self-loop row (every group loads its own node's row slice)
  {
    uint4 q0 = T8[(size_t)v * 8 + sub];
    ACC8(a0, q0);
  }
  int e = beg;
  for (; e + 4 <= lim; e += 4) {
    int s0 = colS[e - ebeg];
    int s1 = colS[e - ebeg + 1];
    int s2 = colS[e - ebeg + 2];
    int s3 = colS[e - ebeg + 3];
    uint4 q0 = T8[(size_t)s0 * 8 + sub];
    uint4 q1 = T8[(size_t)s1 * 8 + sub];
    uint4 q2 = T8[(size_t)s2 * 8 + sub];
    uint4 q3 = T8[(size_t)s3 * 8 + sub];
    ACC8(a0, q0);
    ACC8(a1, q1);
    ACC8(a0, q2);
    ACC8(a1, q3);
  }
  for (; e < lim; ++e) {
    int s0 = colS[e - ebeg];
    uint4 q0 = T8[(size_t)s0 * 8 + sub];
    ACC8(a0, q0);
  }
  // overflow fallback (cold; only if block range exceeded CAPE)
  for (; e < end; ++e) {
    int s0 = col[e];
    uint4 q0 = T8[(size_t)s0 * 8 + sub];
    ACC8(a0, q0);
  }
  float di = dinv[v];
  const float4* __restrict__ b4 = (const float4*)bias;
  float4 bA = b4[sub * 2], bB = b4[sub * 2 + 1];
  float4 rA, rB;
  rA.x = di * (a0[0] + a1[0]) + bA.x;
  rA.y = di * (a0[1] + a1[1]) + bA.y;
  rA.z = di * (a0[2] + a1[2]) + bA.z;
  rA.w = di * (a0[3] + a1[3]) + bA.w;
  rB.x = di * (a0[4] + a1[4]) + bB.x;
  rB.y = di * (a0[5] + a1[5]) + bB.y;
  rB.z = di * (a0[6] + a1[6]) + bB.z;
  rB.w = di * (a0[7] + a1[7]) + bB.w;
  rA.x = rA.x > 0.f ? rA.x : 0.f;  rA.y = rA.y > 0.f ? rA.y : 0.f;
  rA.z = rA.z > 0.f ? rA.z : 0.f;  rA.w = rA.w > 0.f ? rA.w : 0.f;
  rB.x = rB.x > 0.f ? rB.x : 0.f;  rB.y = rB.y > 0.f ? rB.y : 0.f;
  rB.z = rB.z > 0.f ? rB.z : 0.f;  rB.w = rB.w > 0.f ? rB.w : 0.f;
  if (valid) {
    if constexpr (MODE == 0) {
      f16x8 o;
      o[0] = (_Float16)rA.x; o[1] = (_Float16)rA.y;
      o[2] = (_Float16)rA.z; o[3] = (_Float16)rA.w;
      o[4] = (_Float16)rB.x; o[5] = (_Float16)rB.y;
      o[6] = (_Float16)rB.z; o[7] = (_Float16)rB.w;
      uint4* __restrict__ o4 = (uint4*)((__half*)Hout + (size_t)v * HID + sub * 8);
      *o4 = *(uint4*)&o;
    } else {
      float4* __restrict__ o = (float4*)((float*)Hout + (size_t)v * HID + sub * 8);
      o[0] = rA;
      o[1] = rB;
    }
  }
}

// ---------------------------------------------------------------------------
// Fused MLP head: out = relu(H @ Wp1 + bp1) @ Wp2 + bp2, thread-per-node.
// fp32 H input — R9 lesson: the fp16-load variant spilled h[16] to scratch
// (VGPR 256, 10.7MB writes, 47us). This exact fp32 version is measured-good.
// ---------------------------------------------------------------------------
__global__ __launch_bounds__(256) void mlp_head(const float* __restrict__ H,
                                                const float* __restrict__ Wp1,
                                                const float* __restrict__ bp1,
                                                const float* __restrict__ Wp2,
                                                const float* __restrict__ bp2,
                                                float* __restrict__ out, int n) {
  __shared__ float W1t[32 * 64];
  __shared__ float w2s[32];
  __shared__ float b1s[32];
  for (int i = threadIdx.x; i < 64 * 32; i += 256) {
    int k = i >> 5, j = i & 31;
    W1t[j * 64 + k] = Wp1[i];
  }
  if (threadIdx.x < 32) {
    w2s[threadIdx.x] = Wp2[threadIdx.x];
    b1s[threadIdx.x] = bp1[threadIdx.x];
  }
  __syncthreads();
  int node = blockIdx.x * 256 + threadIdx.x;
  if (node >= n) return;
  float4 h[16];
  const float4* __restrict__ hr = (const float4*)(H + (size_t)node * 64);
#pragma unroll
  for (int j = 0; j < 16; j++) h[j] = hr[j];
  float o = bp2[0];
#pragma unroll
  for (int j = 0; j < 32; j++) {
    const float4* wr = (const float4*)(W1t + j * 64);
    float4 a4 = make_float4(0.f, 0.f, 0.f, 0.f);
#pragma unroll
    for (int k = 0; k < 16; k++) {
      float4 w = wr[k];
      a4.x += h[k].x * w.x;
      a4.y += h[k].y * w.y;
      a4.z += h[k].z * w.z;
      a4.w += h[k].w * w.w;
    }
    float a = a4.x + a4.y + a4.z + a4.w + b1s[j];
    a = a > 0.f ? a : 0.f;
    o += a * w2s[j];
  }
  out[node] = o;
}

// ---------------------------------------------------------------------------
extern "C" void kernel_launch(void* const* d_in, const int* in_sizes, int n_in,
                              void* d_out, int out_size, void* d_ws, size_t ws_size,
                              hipStream_t stream) {
  const float* x   = (const float*)d_in[0];
  const int* edge  = (const int*)d_in[1];
  const float* W1  = (const float*)d_in[3];
  const float* b1  = (const float*)d_in[4];
  const float* W2  = (const float*)d_in[5];
  const float* b2  = (const float*)d_in[6];
  const float* W3  = (const float*)d_in[7];
  const float* b3  = (const float*)d_in[8];
  const float* Wp1 = (const float*)d_in[9];
  const float* bp1 = (const float*)d_in[10];
  const float* Wp2 = (const float*)d_in[11];
  const float* bp2 = (const float*)d_in[12];
  float* out = (float*)d_out;

  const int n = in_sizes[0] / NDIM_IN;   // 100000
  const int E = in_sizes[1] / 2;         // 1600000
  const int* src = edge;
  const int* dst = edge + E;

  // workspace carve-out (256B aligned slices)
  char* ws = (char*)d_ws;
  size_t off = 0;
  auto carve = [&](size_t bytes) {
    char* p = ws + off;
    off = (off + bytes + 255) & ~(size_t)255;
    return p;
  };
  int*    histT = (int*)carve((size_t)NB * NC * 4);   // 800 KB (dyn offsets)
  int*    gofs  = (int*)carve(1024 * 4);              // per-bin atomic totals
  int*    bsum  = (int*)carve(1024 * 4);              // scanned bin bases
  int*    tmp   = (int*)carve((size_t)E * 4);         // 6.4 MB (packed)
  int*    col   = (int*)carve((size_t)E * 4);         // 6.4 MB
  int*    rp    = (int*)carve(((size_t)n + 1) * 4);
  float*  dinv  = (float*)carve((size_t)n * 4);
  __half* bufT  = (__half*)carve((size_t)n * HID * 2);
  float*  bufA  = (float*)carve((size_t)n * HID * 4);  // fp32 H (layer 3 only)
  __half* bufH  = (__half*)bufA;  // fp16 H (layers 1-2); lifetime disjoint w/ bufA
  (void)ws_size; (void)n_in; (void)out_size;

  const int nbN = (n + 255) / 256;        // 391
  const int ntiles = (n + 15) >> 4;       // 6250
  const int nbM = 782;                    // mfma gemm blocks (2 tiles/wave)

  hipMemsetAsync(gofs, 0, NB * 4, stream);
  hist_k<<<NC, 1024, 0, stream>>>(dst, histT, gofs, E);
  scatter_k<<<NC, 1024, 0, stream>>>(src, dst, histT, gofs, bsum, tmp, E);
  binsort_k<<<NB, 256, 0, stream>>>(tmp, bsum, col, rp, dinv, n, E);

  const int nbSp = (n + 31) / 32;         // 8 nodes/wave, 32/block

  // layer 1: 128 -> 64  (fp32 in, fp16 H out)
  gemm_mfma<128, 0><<<nbM, 256, 0, stream>>>(x, W1, dinv, bufT, n, ntiles);
  spmm_relu<0><<<nbSp, 256, 0, stream>>>(rp, col, bufT, dinv, b1, bufH, n);
  // layer 2: 64 -> 64   (fp16 in, fp16 H out)
  gemm_mfma<64, 1><<<nbM, 256, 0, stream>>>(bufH, W2, dinv, bufT, n, ntiles);
  spmm_relu<0><<<nbSp, 256, 0, stream>>>(rp, col, bufT, dinv, b2, bufH, n);
  // layer 3: 64 -> 64   (fp16 in, fp32 H out for head)
  gemm_mfma<64, 1><<<nbM, 256, 0, stream>>>(bufH, W3, dinv, bufT, n, ntiles);
  spmm_relu<1><<<nbSp, 256, 0, stream>>>(rp, col, bufT, dinv, b3, bufA, n);
  // head (fp32 H in — measured-good)
  mlp_head<<<nbN, 256, 0, stream>>>(bufA, Wp1, bp1, Wp2, bp2, out, n);
}

// Round 12
// 181.890 us; speedup vs baseline: 1.1526x; 1.0418x over previous
//
#include <hip/hip_runtime.h>
#include <hip/hip_bf16.h>
#include <hip/hip_fp16.h>

#define NDIM_IN 128
#define HID 64

#define BINW 128          // dst values per bin
#define NB   782          // ceil(100000/128)
#define NC   256          // phase-1 block count == scan1 block size (alignment!)
#define CAP  3072         // LDS edge buffer per bin (mean 2046, +22 sigma)
#define CAPE 1024         // staged col indices per spmm block (mean 512, +22 sigma)
#define HSTR 66           // padded LDS row stride in halfs (bank = (t+k)%32, conflict-free)

typedef _Float16 f16x8 __attribute__((ext_vector_type(8)));
typedef float f32x4 __attribute__((ext_vector_type(4)));

// f16-source fused accumulate: acc += f32(f16_half(src)) * 1.0 — bit-identical
// to cvt+add. NOTE: macro params must NOT be named x/y/z/w (R7 lesson).
#define MIX_LO(acc, hsrc) \
  asm("v_fma_mix_f32 %0, %1, %2, %0 op_sel:[0,0,0] op_sel_hi:[1,0,0]" \
      : "+v"(acc) : "v"(hsrc), "v"(one))
#define MIX_HI(acc, hsrc) \
  asm("v_fma_mix_f32 %0, %1, %2, %0 op_sel:[1,0,0] op_sel_hi:[1,0,0]" \
      : "+v"(acc) : "v"(hsrc), "v"(one))
#define ACC8(a, q) do { \
  MIX_LO(a[0], (q).x); MIX_HI(a[1], (q).x); \
  MIX_LO(a[2], (q).y); MIX_HI(a[3], (q).y); \
  MIX_LO(a[4], (q).z); MIX_HI(a[5], (q).z); \
  MIX_LO(a[6], (q).w); MIX_HI(a[7], (q).w); } while (0)

// ---------------------------------------------------------------------------
// Phase 1a: per-block LDS histogram over bins, written transposed.
// (R11 lesson: the atomicAdd range-reservation variant cost +6.5us — 200k
// serialized same-line L2 atomics. scan1 restored.)
// ---------------------------------------------------------------------------
__global__ __launch_bounds__(1024) void hist_k(const int* __restrict__ dst,
                                               int* __restrict__ histT, int E) {
  __shared__ int h[NB];
  for (int i = threadIdx.x; i < NB; i += 1024) h[i] = 0;
  __syncthreads();
  int E4 = E >> 2;
  int chunk = (E4 + NC - 1) / NC;
  int beg = blockIdx.x * chunk;
  int end = min(E4, beg + chunk);
  const int4* __restrict__ d4 = (const int4*)dst;
  for (int i = beg + (int)threadIdx.x; i < end; i += 1024) {
    int4 d = d4[i];
    atomicAdd(&h[d.x >> 7], 1);
    atomicAdd(&h[d.y >> 7], 1);
    atomicAdd(&h[d.z >> 7], 1);
    atomicAdd(&h[d.w >> 7], 1);
  }
  __syncthreads();
  for (int i = threadIdx.x; i < NB; i += 1024)
    histT[i * NC + blockIdx.x] = h[i];
}

// ---------------------------------------------------------------------------
// scan1: block size == NC so bs[bin] becomes the per-bin total (raw).
// (scan2 folded into scatter_k — R8-verified.)
// ---------------------------------------------------------------------------
__global__ __launch_bounds__(256) void scan1(int* __restrict__ g,
                                             int* __restrict__ bs, int len) {
  __shared__ int s[256];
  int t = threadIdx.x;
  int i = blockIdx.x * 256 + t;
  int v = (i < len) ? g[i] : 0;
  s[t] = v;
  __syncthreads();
  for (int off = 1; off < 256; off <<= 1) {
    int x = (t >= off) ? s[t - off] : 0;
    __syncthreads();
    s[t] += x;
    __syncthreads();
  }
  if (i < len) g[i] = s[t] - v;
  if (t == 255) bs[blockIdx.x] = s[255];
}

// ---------------------------------------------------------------------------
// Phase 1c: scatter packed (src<<7 | dst&127) into tmp, grouped by bin.
// Folds scan2: LDS Hillis-Steele of raw bin totals; block 0 publishes bases.
// ---------------------------------------------------------------------------
__global__ __launch_bounds__(1024) void scatter_k(const int* __restrict__ src,
                                                  const int* __restrict__ dst,
                                                  const int* __restrict__ S,
                                                  const int* __restrict__ bs_raw,
                                                  int* __restrict__ bsum_out,
                                                  int* __restrict__ tmp, int E) {
  __shared__ int cur[NB];
  __shared__ int sc[1024];
  int t = threadIdx.x;
  int v = (t < NB) ? bs_raw[t] : 0;
  sc[t] = v;
  __syncthreads();
  for (int off = 1; off < 1024; off <<= 1) {
    int x = (t >= off) ? sc[t - off] : 0;
    __syncthreads();
    sc[t] += x;
    __syncthreads();
  }
  if (t < NB) {
    int ex = sc[t] - v;                       // exclusive bin base
    cur[t] = S[t * NC + blockIdx.x] + ex;
    if (blockIdx.x == 0) bsum_out[t] = ex;    // publish for binsort_k
  }
  __syncthreads();
  int E4 = E >> 2;
  int chunk = (E4 + NC - 1) / NC;
  int beg = blockIdx.x * chunk;
  int end = min(E4, beg + chunk);
  const int4* __restrict__ d4 = (const int4*)dst;
  const int4* __restrict__ s4 = (const int4*)src;
  for (int i = beg + (int)threadIdx.x; i < end; i += 1024) {
    int4 d = d4[i];
    int4 sv = s4[i];
    int p0 = atomicAdd(&cur[d.x >> 7], 1); tmp[p0] = (sv.x << 7) | (d.x & 127);
    int p1 = atomicAdd(&cur[d.y >> 7], 1); tmp[p1] = (sv.y << 7) | (d.y & 127);
    int p2 = atomicAdd(&cur[d.z >> 7], 1); tmp[p2] = (sv.z << 7) | (d.z & 127);
    int p3 = atomicAdd(&cur[d.w >> 7], 1); tmp[p3] = (sv.w << 7) | (d.w & 127);
  }
}

// ---------------------------------------------------------------------------
// Phase 2: one block per bin; in-LDS counting sort -> col, rp, dinv.
// ---------------------------------------------------------------------------
__global__ __launch_bounds__(256) void binsort_k(const int* __restrict__ tmp,
                                                 const int* __restrict__ bsum,
                                                 int* __restrict__ col,
                                                 int* __restrict__ rp,
                                                 float* __restrict__ dinv,
                                                 int n, int E) {
  int bin = blockIdx.x;
  int base = bsum[bin];
  int end = (bin == NB - 1) ? E : bsum[bin + 1];
  int m = end - base;
  __shared__ int cnt[BINW];
  __shared__ int offs[BINW];
  __shared__ int cur[BINW];
  __shared__ int buf[CAP];
  int t = threadIdx.x;
  if (t < BINW) cnt[t] = 0;
  __syncthreads();
  for (int i = t; i < m; i += 256) {
    int p = tmp[base + i];
    atomicAdd(&cnt[p & (BINW - 1)], 1);
  }
  __syncthreads();
  if (t < BINW) offs[t] = cnt[t];
  __syncthreads();
  for (int off = 1; off < BINW; off <<= 1) {
    int x = (t < BINW && t >= off) ? offs[t - off] : 0;
    __syncthreads();
    if (t < BINW) offs[t] += x;
    __syncthreads();
  }
  if (t < BINW) {
    int ex = offs[t] - cnt[t];
    cur[t] = ex;
    int v = bin * BINW + t;
    if (v < n) {
      rp[v] = base + ex;
      dinv[v] = rsqrtf((float)cnt[t] + 1.0f);  // +1 = self loop
    }
  }
  if (bin == NB - 1 && t == 0) rp[n] = E;
  __syncthreads();
  for (int i = t; i < m; i += 256) {
    int p = tmp[base + i];
    int r = atomicAdd(&cur[p & (BINW - 1)], 1);
    if (r < CAP) buf[r] = p >> 7;
  }
  __syncthreads();
  int mm = min(m, CAP);
  for (int i = t; i < mm; i += 256) col[base + i] = buf[i];
}

// ---------------------------------------------------------------------------
// MFMA dense transform: T' = (X @ W) * dinv[row], output fp16.
// FP16IN=1: input rows already fp16 (inter-layer H) -> direct f16x8 loads.
// ---------------------------------------------------------------------------
template <int K, int FP16IN>
__global__ __launch_bounds__(256) void gemm_mfma(const void* __restrict__ Xv,
                                                 const float* __restrict__ W,
                                                 const float* __restrict__ dinv,
                                                 __half* __restrict__ T,
                                                 int n, int ntiles) {
  constexpr int NCH = K / 32;
  __shared__ float Ds[4][16 * 68];
  int wv = threadIdx.x >> 6;
  int lane = threadIdx.x & 63;
  int colx = lane & 15;
  int quad = lane >> 4;

  // B fragments: whole W, fp16, stationary
  f16x8 bf[4][NCH];
#pragma unroll
  for (int t = 0; t < 4; t++)
#pragma unroll
    for (int c = 0; c < NCH; c++) {
      f16x8 b;
#pragma unroll
      for (int j = 0; j < 8; j++)
        b[j] = (_Float16)W[(32 * c + quad * 8 + j) * 64 + 16 * t + colx];
      bf[t][c] = b;
    }

  for (int tile = blockIdx.x * 4 + wv; tile < ntiles; tile += gridDim.x * 4) {
    int node0 = tile * 16;
    f32x4 acc[4] = {{0.f, 0.f, 0.f, 0.f}, {0.f, 0.f, 0.f, 0.f},
                    {0.f, 0.f, 0.f, 0.f}, {0.f, 0.f, 0.f, 0.f}};
    int arow = min(node0 + colx, n - 1);
#pragma unroll
    for (int c = 0; c < NCH; c++) {
      f16x8 a;
      if constexpr (FP16IN) {
        const _Float16* __restrict__ xr = (const _Float16*)Xv + (size_t)arow * K;
        a = *(const f16x8*)(xr + 32 * c + quad * 8);
      } else {
        const float* __restrict__ xr = (const float*)Xv + (size_t)arow * K;
        float4 x0 = *(const float4*)(xr + 32 * c + quad * 8);
        float4 x1 = *(const float4*)(xr + 32 * c + quad * 8 + 4);
        a[0] = (_Float16)x0.x; a[1] = (_Float16)x0.y;
        a[2] = (_Float16)x0.z; a[3] = (_Float16)x0.w;
        a[4] = (_Float16)x1.x; a[5] = (_Float16)x1.y;
        a[6] = (_Float16)x1.z; a[7] = (_Float16)x1.w;
      }
#pragma unroll
      for (int t = 0; t < 4; t++)
        acc[t] = __builtin_amdgcn_mfma_f32_16x16x32_f16(a, bf[t][c], acc[t], 0, 0, 0);
    }
    // epilogue: scale rows by dinv, transpose through LDS, emit fp16
    float dv[4];
#pragma unroll
    for (int r = 0; r < 4; r++) {
      int nd = min(node0 + quad * 4 + r, n - 1);
      dv[r] = dinv[nd];
    }
#pragma unroll
    for (int t = 0; t < 4; t++)
#pragma unroll
      for (int r = 0; r < 4; r++)
        Ds[wv][(quad * 4 + r) * 68 + 16 * t + colx] = acc[t][r] * dv[r];
    int nd = node0 + colx;
    const float* __restrict__ row = &Ds[wv][colx * 68 + quad * 16];
    float4 y0 = *(const float4*)(row + 0);
    float4 y1 = *(const float4*)(row + 4);
    float4 y2 = *(const float4*)(row + 8);
    float4 y3 = *(const float4*)(row + 12);
    f16x8 o0, o1;
    o0[0] = (_Float16)y0.x; o0[1] = (_Float16)y0.y;
    o0[2] = (_Float16)y0.z; o0[3] = (_Float16)y0.w;
    o0[4] = (_Float16)y1.x; o0[5] = (_Float16)y1.y;
    o0[6] = (_Float16)y1.z; o0[7] = (_Float16)y1.w;
    o1[0] = (_Float16)y2.x; o1[1] = (_Float16)y2.y;
    o1[2] = (_Float16)y2.z; o1[3] = (_Float16)y2.w;
    o1[4] = (_Float16)y3.x; o1[5] = (_Float16)y3.y;
    o1[6] = (_Float16)y3.z; o1[7] = (_Float16)y3.w;
    if (nd < n) {
      uint4* __restrict__ o = (uint4*)(T + (size_t)nd * 64 + quad * 16);
      o[0] = *(uint4*)&o0;
      o[1] = *(uint4*)&o1;
    }
  }
}

// ---------------------------------------------------------------------------
// SpMM gather: GROUP-per-node, LDS-staged col indices, 4-edge unroll /
// 2 accumulator sets (R8-measured best; 8-edge crosses the 64-VGPR cliff),
// v_fma_mix accumulate. Always emits fp16 H.
// ---------------------------------------------------------------------------
__global__ __launch_bounds__(256) void spmm_relu(const int* __restrict__ rp,
                                                 const int* __restrict__ col,
                                                 const __half* __restrict__ T,
                                                 const float* __restrict__ dinv,
                                                 const float* __restrict__ bias,
                                                 __half* __restrict__ Hout, int n) {
  __shared__ int colS[CAPE];
  int v0 = blockIdx.x * 32;
  int ebeg = rp[v0];
  int eend = rp[min(v0 + 32, n)];
  int m = eend - ebeg;
  int mstage = min(m, CAPE);
  for (int i = threadIdx.x; i < mstage; i += 256) colS[i] = col[ebeg + i];
  __syncthreads();

  int lane = threadIdx.x & 63;
  int wv = threadIdx.x >> 6;
  int g = lane >> 3;
  int sub = lane & 7;
  int v = v0 + wv * 8 + g;
  bool valid = v < n;
  if (!valid) v = n - 1;
  const uint4* __restrict__ T8 = (const uint4*)T;
  int beg = rp[v];
  int end = rp[v + 1];
  int lim = min(end, ebeg + CAPE);   // staged portion of this node's edges

  float one = 1.0f;
  float a0[8], a1[8];
#pragma unroll
  for (int j = 0; j < 8; j++) { a0[j] = 0.f; a1[j] = 0.f; }
  // self-loop row (every group loads its own node's row slice)
  {
    uint4 q0 = T8[(size_t)v * 8 + sub];
    ACC8(a0, q0);
  }
  int e = beg;
  for (; e + 4 <= lim; e += 4) {
    int s0 = colS[e - ebeg];
    int s1 = colS[e - ebeg + 1];
    int s2 = colS[e - ebeg + 2];
    int s3 = colS[e - ebeg + 3];
    uint4 q0 = T8[(size_t)s0 * 8 + sub];
    uint4 q1 = T8[(size_t)s1 * 8 + sub];
    uint4 q2 = T8[(size_t)s2 * 8 + sub];
    uint4 q3 = T8[(size_t)s3 * 8 + sub];
    ACC8(a0, q0);
    ACC8(a1, q1);
    ACC8(a0, q2);
    ACC8(a1, q3);
  }
  for (; e < lim; ++e) {
    int s0 = colS[e - ebeg];
    uint4 q0 = T8[(size_t)s0 * 8 + sub];
    ACC8(a0, q0);
  }
  // overflow fallback (cold; only if block range exceeded CAPE)
  for (; e < end; ++e) {
    int s0 = col[e];
    uint4 q0 = T8[(size_t)s0 * 8 + sub];
    ACC8(a0, q0);
  }
  float di = dinv[v];
  const float4* __restrict__ b4 = (const float4*)bias;
  float4 bA = b4[sub * 2], bB = b4[sub * 2 + 1];
  float4 rA, rB;
  rA.x = di * (a0[0] + a1[0]) + bA.x;
  rA.y = di * (a0[1] + a1[1]) + bA.y;
  rA.z = di * (a0[2] + a1[2]) + bA.z;
  rA.w = di * (a0[3] + a1[3]) + bA.w;
  rB.x = di * (a0[4] + a1[4]) + bB.x;
  rB.y = di * (a0[5] + a1[5]) + bB.y;
  rB.z = di * (a0[6] + a1[6]) + bB.z;
  rB.w = di * (a0[7] + a1[7]) + bB.w;
  rA.x = rA.x > 0.f ? rA.x : 0.f;  rA.y = rA.y > 0.f ? rA.y : 0.f;
  rA.z = rA.z > 0.f ? rA.z : 0.f;  rA.w = rA.w > 0.f ? rA.w : 0.f;
  rB.x = rB.x > 0.f ? rB.x : 0.f;  rB.y = rB.y > 0.f ? rB.y : 0.f;
  rB.z = rB.z > 0.f ? rB.z : 0.f;  rB.w = rB.w > 0.f ? rB.w : 0.f;
  if (valid) {
    f16x8 o;
    o[0] = (_Float16)rA.x; o[1] = (_Float16)rA.y;
    o[2] = (_Float16)rA.z; o[3] = (_Float16)rA.w;
    o[4] = (_Float16)rB.x; o[5] = (_Float16)rB.y;
    o[6] = (_Float16)rB.z; o[7] = (_Float16)rB.w;
    uint4* __restrict__ o4 = (uint4*)(Hout + (size_t)v * HID + sub * 8);
    *o4 = *(uint4*)&o;
  }
}

// ---------------------------------------------------------------------------
// MLP head, fp16 H input via padded-LDS staging (R9 lesson: the register
// variant `(__half2*)&local_uint4` spilled h[16] to scratch — VGPR 256,
// 10.7MB writes, 47us. This version never takes the address of a local:
// stage the block's 256 rows into LDS (stride 66 halfs -> bank (t+k)%32,
// conflict-free), operands read directly from LDS. Halves the H round-trip.
// ---------------------------------------------------------------------------
__global__ __launch_bounds__(256) void mlp_head(const __half* __restrict__ H,
                                                const float* __restrict__ Wp1,
                                                const float* __restrict__ bp1,
                                                const float* __restrict__ Wp2,
                                                const float* __restrict__ bp2,
                                                float* __restrict__ out, int n) {
  __shared__ float W1t[32 * 64];
  __shared__ float w2s[32];
  __shared__ float b1s[32];
  __shared__ __half Hs[256 * HSTR];   // 33.8 KB
  for (int i = threadIdx.x; i < 64 * 32; i += 256) {
    int k = i >> 5, j = i & 31;
    W1t[j * 64 + k] = Wp1[i];
  }
  if (threadIdx.x < 32) {
    w2s[threadIdx.x] = Wp2[threadIdx.x];
    b1s[threadIdx.x] = bp1[threadIdx.x];
  }
  int base = blockIdx.x * 256;
  int nrow = min(256, n - base);
  const __half2* __restrict__ g2 = (const __half2*)(H + (size_t)base * 64);
  __half2* __restrict__ s2 = (__half2*)Hs;       // padded stride = 33 h2/row
  for (int i = threadIdx.x; i < nrow * 32; i += 256) {
    int r = i >> 5, c = i & 31;
    s2[r * 33 + c] = g2[i];
  }
  __syncthreads();
  int t = threadIdx.x;
  int node = base + t;
  if (node >= n) return;
  const __half2* __restrict__ hrow = s2 + t * 33;
  float o = bp2[0];
#pragma unroll
  for (int j = 0; j < 32; j++) {
    const float4* wr = (const float4*)(W1t + j * 64);
    float a = b1s[j];
#pragma unroll
    for (int k2 = 0; k2 < 32; k2 += 2) {
      float2 f0 = __half22float2(hrow[k2]);
      float2 f1 = __half22float2(hrow[k2 + 1]);
      float4 w = wr[k2 >> 1];
      a += f0.x * w.x + f0.y * w.y + f1.x * w.z + f1.y * w.w;
    }
    a = a > 0.f ? a : 0.f;
    o += a * w2s[j];
  }
  out[node] = o;
}

// ---------------------------------------------------------------------------
extern "C" void kernel_launch(void* const* d_in, const int* in_sizes, int n_in,
                              void* d_out, int out_size, void* d_ws, size_t ws_size,
                              hipStream_t stream) {
  const float* x   = (const float*)d_in[0];
  const int* edge  = (const int*)d_in[1];
  const float* W1  = (const float*)d_in[3];
  const float* b1  = (const float*)d_in[4];
  const float* W2  = (const float*)d_in[5];
  const float* b2  = (const float*)d_in[6];
  const float* W3  = (const float*)d_in[7];
  const float* b3  = (const float*)d_in[8];
  const float* Wp1 = (const float*)d_in[9];
  const float* bp1 = (const float*)d_in[10];
  const float* Wp2 = (const float*)d_in[11];
  const float* bp2 = (const float*)d_in[12];
  float* out = (float*)d_out;

  const int n = in_sizes[0] / NDIM_IN;   // 100000
  const int E = in_sizes[1] / 2;         // 1600000
  const int* src = edge;
  const int* dst = edge + E;

  // workspace carve-out (256B aligned slices)
  char* ws = (char*)d_ws;
  size_t off = 0;
  auto carve = [&](size_t bytes) {
    char* p = ws + off;
    off = (off + bytes + 255) & ~(size_t)255;
    return p;
  };
  int*    histT = (int*)carve((size_t)NB * NC * 4);   // 800 KB
  int*    bsraw = (int*)carve(1024 * 4);              // raw per-bin totals
  int*    bsum  = (int*)carve(1024 * 4);              // scanned bin bases
  int*    tmp   = (int*)carve((size_t)E * 4);         // 6.4 MB (packed)
  int*    col   = (int*)carve((size_t)E * 4);         // 6.4 MB
  int*    rp    = (int*)carve(((size_t)n + 1) * 4);
  float*  dinv  = (float*)carve((size_t)n * 4);
  __half* bufT  = (__half*)carve((size_t)n * HID * 2);
  __half* bufH  = (__half*)carve((size_t)n * HID * 2);
  (void)ws_size; (void)n_in; (void)out_size;

  const int nbN = (n + 255) / 256;        // 391
  const int ntiles = (n + 15) >> 4;       // 6250
  const int nbM = 782;                    // mfma gemm blocks (2 tiles/wave)
  const int scan_len = NB * NC;           // 200192
  const int nbScan = (scan_len + 255) / 256;  // 782 == NB (alignment!)

  hist_k<<<NC, 1024, 0, stream>>>(dst, histT, E);
  scan1<<<nbScan, 256, 0, stream>>>(histT, bsraw, scan_len);
  scatter_k<<<NC, 1024, 0, stream>>>(src, dst, histT, bsraw, bsum, tmp, E);
  binsort_k<<<NB, 256, 0, stream>>>(tmp, bsum, col, rp, dinv, n, E);

  const int nbSp = (n + 31) / 32;         // 8 nodes/wave, 32/block

  // layer 1: 128 -> 64  (fp32 in, fp16 H out)
  gemm_mfma<128, 0><<<nbM, 256, 0, stream>>>(x, W1, dinv, bufT, n, ntiles);
  spmm_relu<<<nbSp, 256, 0, stream>>>(rp, col, bufT, dinv, b1, bufH, n);
  // layer 2: 64 -> 64   (fp16 in, fp16 H out)
  gemm_mfma<64, 1><<<nbM, 256, 0, stream>>>(bufH, W2, dinv, bufT, n, ntiles);
  spmm_relu<<<nbSp, 256, 0, stream>>>(rp, col, bufT, dinv, b2, bufH, n);
  // layer 3: 64 -> 64   (fp16 in, fp16 H out)
  gemm_mfma<64, 1><<<nbM, 256, 0, stream>>>(bufH, W3, dinv, bufT, n, ntiles);
  spmm_relu<<<nbSp, 256, 0, stream>>>(rp, col, bufT, dinv, b3, bufH, n);
  // head (fp16 H in via LDS staging)
  mlp_head<<<nbN, 256, 0, stream>>>(bufH, Wp1, bp1, Wp2, bp2, out, n);
}